// Round 1
// baseline (53.361 us; speedup 1.0000x reference)
//
#include <hip/hip_runtime.h>

#define N_NODES 2048
#define WORDS   64          // N_NODES / 32
#define E_MAX_OUT 1048576
#define FDIM    8

// ---------------- init: fill d_out pattern + zero A bitset ----------------
__global__ void k_init(float* __restrict__ out, unsigned* __restrict__ a_bits) {
    int tid = blockIdx.x * blockDim.x + threadIdx.x;
    int nthreads = gridDim.x * blockDim.x;
    const int TOTAL4 = (2 * E_MAX_OUT + FDIM * E_MAX_OUT) / 4;  // 2,621,440 float4
    const int NEG4   = (2 * E_MAX_OUT) / 4;                     // 524,288 float4 of -1
    float4* o4 = (float4*)out;
    for (int p = tid; p < TOTAL4; p += nthreads) {
        float v = (p < NEG4) ? -1.0f : 0.0f;
        o4[p] = make_float4(v, v, v, v);
    }
    for (int p = tid; p < N_NODES * WORDS; p += nthreads) a_bits[p] = 0u;
}

// ---------------- build adjacency bitset ----------------
__global__ void k_build(const int* __restrict__ ei, int E, unsigned* __restrict__ a_bits) {
    int e = blockIdx.x * blockDim.x + threadIdx.x;
    if (e >= E) return;
    int s = ei[e];
    int d = ei[E + e];
    atomicOr(&a_bits[s * WORDS + (d >> 5)], 1u << (d & 31));
}

// ---------------- two-hop: C[i] = A[i] | (OR_{k in nbr(i)} A[k]) & ~eye ----------------
__global__ void __launch_bounds__(64) k_twohop(const unsigned* __restrict__ a_bits,
                                               unsigned* __restrict__ c_bits,
                                               int* __restrict__ row_cnt) {
    int i = blockIdx.x;
    int t = threadIdx.x;                 // word index 0..63
    __shared__ unsigned rowi[WORDS];
    rowi[t] = a_bits[i * WORDS + t];
    __syncthreads();

    unsigned acc = 0u;
    for (int w = 0; w < WORDS; ++w) {
        unsigned bits = rowi[w];
        while (bits) {
            int k = (w << 5) + __ffs(bits) - 1;
            bits &= bits - 1;
            acc |= a_bits[k * WORDS + t];
        }
    }
    if (t == (i >> 5)) acc &= ~(1u << (i & 31));   // remove_self_loops on two-hop
    acc |= rowi[t];                                 // union with original edges
    c_bits[i * WORDS + t] = acc;

    int cnt = __popc(acc);
    for (int off = 32; off; off >>= 1) cnt += __shfl_down(cnt, off, 64);
    if (t == 0) row_cnt[i] = cnt;
}

// ---------------- exclusive prefix sum over 2048 row counts (1 wave) ----------------
__global__ void __launch_bounds__(64) k_scan(const int* __restrict__ row_cnt,
                                             int* __restrict__ row_off) {
    int t = threadIdx.x;
    int base = t * 32;
    int s = 0;
    for (int j = 0; j < 32; ++j) s += row_cnt[base + j];
    int incl = s;
    for (int off = 1; off < 64; off <<= 1) {
        int v = __shfl_up(incl, off, 64);
        if (t >= off) incl += v;
    }
    int run = incl - s;   // exclusive
    for (int j = 0; j < 32; ++j) {
        row_off[base + j] = run;
        run += row_cnt[base + j];
    }
    if (t == 63) row_off[N_NODES] = incl;
}

// ---------------- emit edge_index in row-major nonzero order ----------------
__global__ void __launch_bounds__(64) k_emit(const unsigned* __restrict__ c_bits,
                                             const int* __restrict__ row_off,
                                             float* __restrict__ out) {
    int i = blockIdx.x;
    int t = threadIdx.x;
    unsigned c = c_bits[i * WORDS + t];
    int pc = __popc(c);
    int incl = pc;
    for (int off = 1; off < 64; off <<= 1) {
        int v = __shfl_up(incl, off, 64);
        if (t >= off) incl += v;
    }
    int p = row_off[i] + incl - pc;     // exclusive within-row base for this word
    float fi = (float)i;
    int wbase = t << 5;
    unsigned bits = c;
    while (bits) {
        int b = __ffs(bits) - 1;
        bits &= bits - 1;
        if (p < E_MAX_OUT) {
            out[p]             = fi;                  // rows
            out[E_MAX_OUT + p] = (float)(wbase + b);  // cols
        }
        ++p;
    }
}

// ---------------- scatter summed attrs of original edges ----------------
__global__ void k_attr(const int* __restrict__ ei, const float* __restrict__ attr, int E,
                       const unsigned* __restrict__ c_bits, const int* __restrict__ row_off,
                       float* __restrict__ out_attr) {
    int e = blockIdx.x * blockDim.x + threadIdx.x;
    if (e >= E) return;
    int s = ei[e];
    int d = ei[E + e];
    const unsigned* row = c_bits + s * WORDS;
    int dw = d >> 5;
    int r = 0;
    for (int w = 0; w < dw; ++w) r += __popc(row[w]);
    r += __popc(row[dw] & ((1u << (d & 31)) - 1u));
    int p = row_off[s] + r;
    if (p < E_MAX_OUT) {
        for (int f = 0; f < FDIM; ++f)
            atomicAdd(&out_attr[p * FDIM + f], attr[e * FDIM + f]);
    }
}

extern "C" void kernel_launch(void* const* d_in, const int* in_sizes, int n_in,
                              void* d_out, int out_size, void* d_ws, size_t ws_size,
                              hipStream_t stream) {
    const int*   ei   = (const int*)d_in[1];     // [2, E] : src row then dst row
    const float* attr = (const float*)d_in[2];   // [E, 8]
    int E = in_sizes[1] / 2;

    float* out = (float*)d_out;                  // rows | cols | attrs (all float32)
    unsigned char* ws = (unsigned char*)d_ws;
    unsigned* a_bits  = (unsigned*)(ws);                       // 512 KB
    unsigned* c_bits  = (unsigned*)(ws + 512 * 1024);          // 512 KB
    int*      row_cnt = (int*)(ws + 1024 * 1024);              // 8 KB
    int*      row_off = (int*)(ws + 1024 * 1024 + 16 * 1024);  // 8 KB + 4

    k_init  <<<2048, 256, 0, stream>>>(out, a_bits);
    k_build <<<(E + 255) / 256, 256, 0, stream>>>(ei, E, a_bits);
    k_twohop<<<N_NODES, 64, 0, stream>>>(a_bits, c_bits, row_cnt);
    k_scan  <<<1, 64, 0, stream>>>(row_cnt, row_off);
    k_emit  <<<N_NODES, 64, 0, stream>>>(c_bits, row_off, out);
    k_attr  <<<(E + 255) / 256, 256, 0, stream>>>(ei, attr, E, c_bits, row_off,
                                                  out + 2 * E_MAX_OUT);
}